// Round 1
// baseline (411.286 us; speedup 1.0000x reference)
//
#include <hip/hip_runtime.h>

#define Bdim 8
#define Tdim 100
#define Sdim 400
#define Kk   8
#define Hdim 512
#define Vdim 32000
#define Mdim (Bdim * Tdim)   // 800

typedef __attribute__((ext_vector_type(8))) short short8;     // 8 bf16 = 4 VGPRs
typedef __attribute__((ext_vector_type(4))) float float4_t;   // MFMA acc

static __device__ __forceinline__ unsigned short f2bf(float f) {
    unsigned int x = __float_as_uint(f);
    unsigned int r = (x + 0x7fffu + ((x >> 16) & 1u)) >> 16;   // RNE
    return (unsigned short)r;
}

// ---------------- prep: dec_out fp32 -> bf16 ----------------
__global__ void convert_a_kernel(const float* __restrict__ A, unsigned short* __restrict__ Abf, int n) {
    int i = blockIdx.x * blockDim.x + threadIdx.x;
    if (i < n) Abf[i] = f2bf(A[i]);
}

// ---------------- prep: W (512 x 32000) fp32 -> WT (32000 x 512) bf16 ----------------
__global__ void transpose_kernel(const float* __restrict__ W, unsigned short* __restrict__ WT) {
    __shared__ float tile[32][33];
    int k0 = blockIdx.y * 32;
    int v0 = blockIdx.x * 32;
    int tx = threadIdx.x & 31;
    int ty = threadIdx.x >> 5;           // 0..7
#pragma unroll
    for (int i = 0; i < 32; i += 8)
        tile[ty + i][tx] = W[(k0 + ty + i) * Vdim + v0 + tx];
    __syncthreads();
#pragma unroll
    for (int i = 0; i < 32; i += 8) {
        int v = v0 + ty + i;
        WT[v * Hdim + k0 + tx] = f2bf(tile[tx][ty + i]);
    }
}

// ---------------- GEMM: logits(800x32000) = Abf(800x512) * WT^T + bias ----------------
// block = 256 threads (4 waves). Per wave: 128m x 32n. Block: 128m x 128n.
// grid = (7, 250). LDS-free: fragments loaded straight from global (16B/lane).
__global__ __launch_bounds__(256) void gemm_kernel(const unsigned short* __restrict__ Abf,
                                                   const unsigned short* __restrict__ WT,
                                                   const float* __restrict__ bias,
                                                   float* __restrict__ logits) {
    int lane = threadIdx.x & 63;
    int wave = threadIdx.x >> 6;
    int l15  = lane & 15;
    int kq   = lane >> 4;                 // 0..3
    int m_base = blockIdx.x * 128;        // up to 768 (rows 768..895 partially masked)
    int n_base = blockIdx.y * 128 + wave * 32;

    const unsigned short* aptr[8];
#pragma unroll
    for (int i = 0; i < 8; ++i) {
        int m = m_base + i * 16 + l15;
        if (m >= Mdim) m = Mdim - 1;      // clamp; stores masked later
        aptr[i] = Abf + m * Hdim + kq * 8;
    }
    const unsigned short* bptr[2];
#pragma unroll
    for (int j = 0; j < 2; ++j)
        bptr[j] = WT + (n_base + j * 16 + l15) * Hdim + kq * 8;

    float4_t acc[8][2] = {};
    short8 afrag[2][8];
    short8 bfrag[2][2];

    // preload K-step 0
#pragma unroll
    for (int i = 0; i < 8; ++i) afrag[0][i] = *(const short8*)(aptr[i]);
#pragma unroll
    for (int j = 0; j < 2; ++j) bfrag[0][j] = *(const short8*)(bptr[j]);

#pragma unroll
    for (int kt = 0; kt < 16; ++kt) {
        int nxt = (kt + 1) & 1;
        if (kt + 1 < 16) {
            int ko = (kt + 1) * 32;
#pragma unroll
            for (int i = 0; i < 8; ++i) afrag[nxt][i] = *(const short8*)(aptr[i] + ko);
#pragma unroll
            for (int j = 0; j < 2; ++j) bfrag[nxt][j] = *(const short8*)(bptr[j] + ko);
        }
        int cur = kt & 1;
#pragma unroll
        for (int i = 0; i < 8; ++i)
#pragma unroll
            for (int j = 0; j < 2; ++j)
                acc[i][j] = __builtin_amdgcn_mfma_f32_16x16x32_bf16(afrag[cur][i], bfrag[cur][j],
                                                                    acc[i][j], 0, 0, 0);
    }

    // epilogue: D[row][col], col = lane&15 (n), row = (lane>>4)*4 + r (m)
#pragma unroll
    for (int j = 0; j < 2; ++j) {
        int n = n_base + j * 16 + l15;
        float bj = bias[n];
#pragma unroll
        for (int i = 0; i < 8; ++i) {
            int mrow = m_base + i * 16 + kq * 4;
#pragma unroll
            for (int r = 0; r < 4; ++r) {
                if (mrow + r < Mdim)
                    logits[(mrow + r) * Vdim + n] = acc[i][j][r] + bj;
            }
        }
    }
}

// ---------------- combine: softmax stats + sparse copy-dist scatter + log blend ----------------
// one block (512 threads) per (b,t) row; V handled in two 16000-wide halves (64 KB LDS).
#define VHALF 16000
__global__ __launch_bounds__(512) void combine_kernel(const float* __restrict__ logits,
                                                      const float* __restrict__ weights,
                                                      const float* __restrict__ p_trans,
                                                      const float* __restrict__ trans_probs,
                                                      const float* __restrict__ probs,
                                                      const int* __restrict__ idxes,
                                                      float* __restrict__ out) {
    __shared__ __align__(16) float ts[VHALF];
    __shared__ float red[16];

    int bt = blockIdx.x;           // 0..799
    int b  = bt / Tdim;
    int tid = threadIdx.x;
    int lane = tid & 63;
    int wid  = tid >> 6;           // 0..7

    const float4* lrow4 = (const float4*)(logits + (size_t)bt * Vdim);

    // ---- pass 1: row max ----
    float mloc = -3.4e38f;
    for (int i = tid; i < Vdim / 4; i += 512) {
        float4 x = lrow4[i];
        mloc = fmaxf(mloc, fmaxf(fmaxf(x.x, x.y), fmaxf(x.z, x.w)));
    }
#pragma unroll
    for (int off = 32; off > 0; off >>= 1)
        mloc = fmaxf(mloc, __shfl_xor(mloc, off, 64));
    if (lane == 0) red[wid] = mloc;
    __syncthreads();
    float mrow = red[0];
#pragma unroll
    for (int w = 1; w < 8; ++w) mrow = fmaxf(mrow, red[w]);

    // ---- pass 2: sum of exp ----
    float sloc = 0.f;
    for (int i = tid; i < Vdim / 4; i += 512) {
        float4 x = lrow4[i];
        sloc += __expf(x.x - mrow) + __expf(x.y - mrow) + __expf(x.z - mrow) + __expf(x.w - mrow);
    }
#pragma unroll
    for (int off = 32; off > 0; off >>= 1)
        sloc += __shfl_xor(sloc, off, 64);
    if (lane == 0) red[8 + wid] = sloc;
    __syncthreads();
    float srow = 0.f;
#pragma unroll
    for (int w = 0; w < 8; ++w) srow += red[8 + w];

    float pt = p_trans[bt];
    float c1 = (1.f - pt) / srow;

    float4* out4 = (float4*)(out + (size_t)bt * Vdim);
    float4* ts4 = (float4*)ts;

    for (int h = 0; h < 2; ++h) {
        // zero accumulator
        float4 z; z.x = z.y = z.z = z.w = 0.f;
        for (int i = tid; i < VHALF / 4; i += 512) ts4[i] = z;
        __syncthreads();

        // sparse scatter: tmp[b,s,idx] += trans_probs*(probs>0.05), weighted by attention
        for (int i = tid; i < Sdim * Kk; i += 512) {
            float pv  = probs[b * (Sdim * Kk) + i];
            float tpv = trans_probs[b * (Sdim * Kk) + i];
            int   idx = idxes[b * (Sdim * Kk) + i];
            int   rel = idx - h * VHALF;
            if (pv > 0.05f && (unsigned)rel < (unsigned)VHALF) {
                int s = i >> 3;
                float w = weights[bt * Sdim + s];
                atomicAdd(&ts[rel], w * tpv);
            }
        }
        __syncthreads();

        // blend + log
        for (int i = tid; i < VHALF / 4; i += 512) {
            float4 x = lrow4[h * (VHALF / 4) + i];
            float4 tv = ts4[i];
            float4 o;
            o.x = __logf(pt * tv.x + c1 * __expf(x.x - mrow));
            o.y = __logf(pt * tv.y + c1 * __expf(x.y - mrow));
            o.z = __logf(pt * tv.z + c1 * __expf(x.z - mrow));
            o.w = __logf(pt * tv.w + c1 * __expf(x.w - mrow));
            out4[h * (VHALF / 4) + i] = o;
        }
        __syncthreads();
    }
}

extern "C" void kernel_launch(void* const* d_in, const int* in_sizes, int n_in,
                              void* d_out, int out_size, void* d_ws, size_t ws_size,
                              hipStream_t stream) {
    const float* dec_out     = (const float*)d_in[0];   // (8,100,512)
    const float* W           = (const float*)d_in[1];   // (512,32000)
    const float* bias        = (const float*)d_in[2];   // (32000,)
    const float* weights     = (const float*)d_in[3];   // (8,100,400)
    const float* p_trans     = (const float*)d_in[4];   // (8,100,1)
    const float* trans_probs = (const float*)d_in[5];   // (8,400,8)
    const float* probs       = (const float*)d_in[6];   // (8,400,8)
    const int*   idxes       = (const int*)d_in[7];     // (8,400,8)
    float* out = (float*)d_out;

    char* wsb = (char*)d_ws;
    unsigned short* Abf = (unsigned short*)wsb;                        // 800*512*2   = 819,200 B
    unsigned short* WT  = (unsigned short*)(wsb + (1u << 20));         // 32000*512*2 = 32.8 MB
    float* logits       = (float*)(wsb + (1u << 20) + 32768000u);      // 800*32000*4 = 102.4 MB

    convert_a_kernel<<<dim3((Mdim * Hdim + 255) / 256), dim3(256), 0, stream>>>(dec_out, Abf, Mdim * Hdim);
    transpose_kernel<<<dim3(Vdim / 32, Hdim / 32), dim3(256), 0, stream>>>(W, WT);
    gemm_kernel<<<dim3(7, Vdim / 128), dim3(256), 0, stream>>>(Abf, WT, bias, logits);
    combine_kernel<<<dim3(Mdim), dim3(512), 0, stream>>>(logits, weights, p_trans, trans_probs,
                                                         probs, idxes, out);
}

// Round 2
// 294.220 us; speedup vs baseline: 1.3979x; 1.3979x over previous
//
#include <hip/hip_runtime.h>

#define Bdim 8
#define Tdim 100
#define Sdim 400
#define Kk   8
#define Hdim 512
#define Vdim 32000
#define Mdim 800          // B*T
#define VHALF 16000

typedef __attribute__((ext_vector_type(8))) short short8;     // 8 bf16 = 4 VGPRs
typedef __attribute__((ext_vector_type(4))) float float4_t;   // MFMA acc

static __device__ __forceinline__ unsigned short f2bf(float f) {
    unsigned int x = __float_as_uint(f);
    return (unsigned short)((x + 0x7fffu + ((x >> 16) & 1u)) >> 16);   // RNE
}
static __device__ __forceinline__ float bf2f(unsigned short h) {
    return __uint_as_float(((unsigned int)h) << 16);
}

// async 16B global->LDS (wave-uniform LDS base + lane*16)
static __device__ __forceinline__ void gload_lds16(const void* g, void* s) {
    __builtin_amdgcn_global_load_lds((const __attribute__((address_space(1))) void*)g,
                                     (__attribute__((address_space(3))) void*)s, 16, 0, 0);
}

// ---------------- zero rowsum ----------------
__global__ void zero_kernel(float* __restrict__ p, int n) {
    int i = blockIdx.x * blockDim.x + threadIdx.x;
    if (i < n) p[i] = 0.f;
}

// ---------------- prep: dec_out fp32 -> bf16 ----------------
__global__ void convert_a_kernel(const float* __restrict__ A, unsigned short* __restrict__ Abf, int n) {
    int i = blockIdx.x * blockDim.x + threadIdx.x;
    if (i < n) Abf[i] = f2bf(A[i]);
}

// ---------------- prep: W (512 x 32000) fp32 -> WT (32000 x 512) bf16 ----------------
__global__ void transpose_kernel(const float* __restrict__ W, unsigned short* __restrict__ WT) {
    __shared__ float tile[32][33];
    int k0 = blockIdx.y * 32;
    int v0 = blockIdx.x * 32;
    int tx = threadIdx.x & 31;
    int ty = threadIdx.x >> 5;           // 0..7
#pragma unroll
    for (int i = 0; i < 32; i += 8)
        tile[ty + i][tx] = W[(k0 + ty + i) * Vdim + v0 + tx];
    __syncthreads();
#pragma unroll
    for (int i = 0; i < 32; i += 8) {
        int v = v0 + ty + i;
        WT[v * Hdim + k0 + tx] = f2bf(tile[tx][ty + i]);
    }
}

// ---------------- GEMM: logits(800x32000) = Abf * WT^T + bias; bf16 store + row sumexp ----
// m97 structure: 128x128 block tile, 4 waves (2x2), 64x64 per wave, BK=64 staged via
// global_load_lds width=16 with XOR chunk swizzle (2-way-only LDS conflicts on ds_read_b128).
__global__ __launch_bounds__(256) void gemm_kernel(const unsigned short* __restrict__ Abf,
                                                   const unsigned short* __restrict__ WT,
                                                   const float* __restrict__ bias,
                                                   unsigned short* __restrict__ logitsbf,
                                                   float* __restrict__ rowsum) {
    __shared__ __align__(16) unsigned short As[128 * 64];   // 16 KB, [row][8 chunks of 8 bf16]
    __shared__ __align__(16) unsigned short Bs[128 * 64];   // 16 KB

    const int tid  = threadIdx.x;
    const int lane = tid & 63;
    const int wave = tid >> 6;
    const int l15  = lane & 15;
    const int kq   = lane >> 4;            // 0..3
    const int m_blk = blockIdx.x * 128;
    const int n_blk = blockIdx.y * 128;
    const int wm = wave & 1, wn = wave >> 1;
    const int m0 = wm * 64, n0 = wn * 64;

    // staging: 1024 16B-chunks per matrix; chunk = (q*4+wave)*64 + lane
    const unsigned short* agp[4];
    const unsigned short* bgp[4];
    unsigned short* alp[4];
    unsigned short* blp[4];
#pragma unroll
    for (int q = 0; q < 4; ++q) {
        int chunk = (q * 4 + wave) * 64 + lane;
        int row = chunk >> 3, c = chunk & 7;
        int gc  = c ^ (row & 7);                 // XOR swizzle: lane fetches the chunk that
        int arow = m_blk + row;                  // belongs at its contiguous LDS slot
        if (arow >= Mdim) arow = Mdim - 1;       // clamp; epilogue masks
        agp[q] = Abf + (size_t)arow * Hdim + gc * 8;
        bgp[q] = WT + (size_t)(n_blk + row) * Hdim + gc * 8;
        alp[q] = As + (q * 4 + wave) * 512;      // wave-uniform base (shorts)
        blp[q] = Bs + (q * 4 + wave) * 512;
    }

    // fragment LDS offsets (shorts): row*64 + ((ks*4+kq)^(row&7))*8
    int a_off[2][4], b_off[2][4];
#pragma unroll
    for (int ks = 0; ks < 2; ++ks)
#pragma unroll
        for (int i = 0; i < 4; ++i) {
            int ra = m0 + i * 16 + l15;
            a_off[ks][i] = ra * 64 + (((ks * 4 + kq) ^ (ra & 7)) * 8);
            int rb = n0 + i * 16 + l15;
            b_off[ks][i] = rb * 64 + (((ks * 4 + kq) ^ (rb & 7)) * 8);
        }

    float4_t acc[4][4] = {};

    for (int kt = 0; kt < 8; ++kt) {
        if (kt) __syncthreads();
        const int ko = kt * 64;
#pragma unroll
        for (int q = 0; q < 4; ++q) {
            gload_lds16(agp[q] + ko, alp[q]);
            gload_lds16(bgp[q] + ko, blp[q]);
        }
        __syncthreads();
#pragma unroll
        for (int ks = 0; ks < 2; ++ks) {
            short8 af[4], bfr[4];
#pragma unroll
            for (int i = 0; i < 4; ++i) af[i]  = *(const short8*)(As + a_off[ks][i]);
#pragma unroll
            for (int j = 0; j < 4; ++j) bfr[j] = *(const short8*)(Bs + b_off[ks][j]);
#pragma unroll
            for (int i = 0; i < 4; ++i)
#pragma unroll
                for (int j = 0; j < 4; ++j)
                    acc[i][j] = __builtin_amdgcn_mfma_f32_16x16x32_bf16(af[i], bfr[j], acc[i][j], 0, 0, 0);
        }
    }

    // epilogue: bias add, bf16 store, per-row partial sum of exp -> atomicAdd rowsum
    float bj[4];
#pragma unroll
    for (int j = 0; j < 4; ++j) bj[j] = bias[n_blk + n0 + j * 16 + l15];

#pragma unroll
    for (int i = 0; i < 4; ++i) {
        float se[4] = {0.f, 0.f, 0.f, 0.f};
        int grow0 = m_blk + m0 + i * 16 + kq * 4;      // + r
#pragma unroll
        for (int j = 0; j < 4; ++j) {
            int col = n_blk + n0 + j * 16 + l15;
#pragma unroll
            for (int r = 0; r < 4; ++r) {
                float v = acc[i][j][r] + bj[j];
                se[r] += __expf(v);
                if (grow0 + r < Mdim)
                    logitsbf[(size_t)(grow0 + r) * Vdim + col] = f2bf(v);
            }
        }
#pragma unroll
        for (int r = 0; r < 4; ++r) {
#pragma unroll
            for (int off = 8; off; off >>= 1)
                se[r] += __shfl_xor(se[r], off, 64);   // reduce over the 16 cols (l15)
        }
        if (l15 == 0) {
#pragma unroll
            for (int r = 0; r < 4; ++r)
                if (grow0 + r < Mdim) atomicAdd(&rowsum[grow0 + r], se[r]);
        }
    }
}

// ---------------- combine: sparse copy-dist scatter + log blend (single logits pass) ----
__global__ __launch_bounds__(512) void combine_kernel(const unsigned short* __restrict__ logitsbf,
                                                      const float* __restrict__ weights,
                                                      const float* __restrict__ p_trans,
                                                      const float* __restrict__ trans_probs,
                                                      const float* __restrict__ probs,
                                                      const int* __restrict__ idxes,
                                                      const float* __restrict__ rowsum,
                                                      float* __restrict__ out) {
    __shared__ __align__(16) float ts[VHALF];

    int bt = blockIdx.x;           // 0..799
    int b  = bt / Tdim;
    int tid = threadIdx.x;

    float pt = p_trans[bt];
    float c1 = (1.f - pt) / rowsum[bt];

    const short8* lrow8 = (const short8*)(logitsbf + (size_t)bt * Vdim);
    float4* out4 = (float4*)(out + (size_t)bt * Vdim);
    float4* ts4  = (float4*)ts;

    for (int h = 0; h < 2; ++h) {
        float4 z = make_float4(0.f, 0.f, 0.f, 0.f);
        for (int i = tid; i < VHALF / 4; i += 512) ts4[i] = z;
        __syncthreads();

        for (int i = tid; i < Sdim * Kk; i += 512) {
            float pv  = probs[b * (Sdim * Kk) + i];
            float tpv = trans_probs[b * (Sdim * Kk) + i];
            int   idx = idxes[b * (Sdim * Kk) + i];
            int   rel = idx - h * VHALF;
            if (pv > 0.05f && (unsigned)rel < (unsigned)VHALF) {
                float w = weights[bt * Sdim + (i >> 3)];
                atomicAdd(&ts[rel], w * tpv);
            }
        }
        __syncthreads();

        for (int i = tid; i < VHALF / 8; i += 512) {
            short8 x8 = lrow8[h * (VHALF / 8) + i];
            float4 t0 = ts4[i * 2];
            float4 t1 = ts4[i * 2 + 1];
            float4 o0, o1;
            o0.x = __logf(pt * t0.x + c1 * __expf(bf2f((unsigned short)x8[0])));
            o0.y = __logf(pt * t0.y + c1 * __expf(bf2f((unsigned short)x8[1])));
            o0.z = __logf(pt * t0.z + c1 * __expf(bf2f((unsigned short)x8[2])));
            o0.w = __logf(pt * t0.w + c1 * __expf(bf2f((unsigned short)x8[3])));
            o1.x = __logf(pt * t1.x + c1 * __expf(bf2f((unsigned short)x8[4])));
            o1.y = __logf(pt * t1.y + c1 * __expf(bf2f((unsigned short)x8[5])));
            o1.z = __logf(pt * t1.z + c1 * __expf(bf2f((unsigned short)x8[6])));
            o1.w = __logf(pt * t1.w + c1 * __expf(bf2f((unsigned short)x8[7])));
            out4[(h * (VHALF / 8) + i) * 2]     = o0;
            out4[(h * (VHALF / 8) + i) * 2 + 1] = o1;
        }
        __syncthreads();
    }
}

extern "C" void kernel_launch(void* const* d_in, const int* in_sizes, int n_in,
                              void* d_out, int out_size, void* d_ws, size_t ws_size,
                              hipStream_t stream) {
    const float* dec_out     = (const float*)d_in[0];   // (8,100,512)
    const float* W           = (const float*)d_in[1];   // (512,32000)
    const float* bias        = (const float*)d_in[2];   // (32000,)
    const float* weights     = (const float*)d_in[3];   // (8,100,400)
    const float* p_trans     = (const float*)d_in[4];   // (8,100,1)
    const float* trans_probs = (const float*)d_in[5];   // (8,400,8)
    const float* probs       = (const float*)d_in[6];   // (8,400,8)
    const int*   idxes       = (const int*)d_in[7];     // (8,400,8)
    float* out = (float*)d_out;

    char* wsb = (char*)d_ws;
    unsigned short* Abf      = (unsigned short*)wsb;                      // 819,200 B
    unsigned short* WT       = (unsigned short*)(wsb + (1ull << 20));     // 32.8 MB
    unsigned short* logitsbf = (unsigned short*)(wsb + (35ull << 20));    // 51.2 MB
    float*          rowsum   = (float*)(wsb + (90ull << 20));             // 3200 B

    zero_kernel<<<dim3(4), dim3(256), 0, stream>>>(rowsum, Mdim);
    convert_a_kernel<<<dim3((Mdim * Hdim + 255) / 256), dim3(256), 0, stream>>>(dec_out, Abf, Mdim * Hdim);
    transpose_kernel<<<dim3(Vdim / 32, Hdim / 32), dim3(256), 0, stream>>>(W, WT);
    gemm_kernel<<<dim3(7, Vdim / 128), dim3(256), 0, stream>>>(Abf, WT, bias, logitsbf, rowsum);
    combine_kernel<<<dim3(Mdim), dim3(512), 0, stream>>>(logitsbf, weights, p_trans, trans_probs,
                                                         probs, idxes, rowsum, out);
}